// Round 6
// baseline (234.911 us; speedup 1.0000x reference)
//
#include <hip/hip_runtime.h>
#include <hip/hip_bf16.h>
#include <math.h>

// Problem constants
#define BB   2
#define CIN  32
#define COUT 32
#define DM   40
#define PD   42                 // padded spatial dim
#define NPTS (DM*DM)            // 1600
#define NVOL (DM*DM*DM)         // 64000
#define EPSBN 1e-5f
#define NSLOT 64                // stat-accumulator slots (spread atomics)

typedef short  bf16x8  __attribute__((ext_vector_type(8)));
typedef short  bf16x4  __attribute__((ext_vector_type(4)));
typedef float  floatx4 __attribute__((ext_vector_type(4)));

// Workspace layout (float offsets), all 16B-aligned
#define WS_WFRAG 0              // bf16[55296] = 27648 floats
#define WS_BCOMB 27648          // 64 floats
#define WS_SUM2  27712          // 64 slots * 64 stats = 4096 floats
#define WS_XPAD2 31808          // bf16[2*42^3*32] = 2370816 floats
#define WS_Y     2402624        // bf16[2*32*64000] = 2048000 floats

#define REPACK_BLOCKS (PD*PD*BB)                  // 3528
#define NW_ELEMS  (2*2*27*64*8)                   // 55296
#define PREP_ELEMS (NW_ELEMS + 64 + NSLOT*64)     // wfrag + bias + zero sums2
#define PREP_BLOCKS ((PREP_ELEMS + 255) / 256)    // 233

static __device__ __forceinline__ short f2bf(float f) {
    __hip_bfloat16 h = __float2bfloat16(f);
    return *reinterpret_cast<short*>(&h);
}
static __device__ __forceinline__ float bf2f(short s) {
    union { unsigned u; float f; } cv;
    cv.u = ((unsigned)(unsigned short)s) << 16;
    return cv.f;
}

// ---------------------------------------------------------------------------
// Kernel 1: fused prep (routing + B-fragment weights + bias + zero stat slots)
//           and channels-last zero-padded bf16 repack of x.
// wfrag[b][ntile][tap][lane][j] = W_b[i=(lane>>4)*8+j][o=ntile*16+(lane&15)][tap]
// ---------------------------------------------------------------------------
__global__ void prep_repack_kernel(const float* __restrict__ x,
                                   const float* __restrict__ emb,
                                   const float* __restrict__ rw,
                                   const float* __restrict__ rb,
                                   const float* __restrict__ ek,
                                   const float* __restrict__ ebias,
                                   float* __restrict__ ws) {
    const int bid = blockIdx.x;
    if (bid < REPACK_BLOCKS) {
        // ---- repack role ----
        int b  = bid / (PD * PD);
        int r  = bid % (PD * PD);
        int zp = r / PD, yp = r % PD;
        __hip_bfloat16* row = (__hip_bfloat16*)(ws + WS_XPAD2) +
                              ((((size_t)b * PD + zp) * PD + yp) * PD) * 32;
        bool inz = (zp >= 1 && zp <= DM && yp >= 1 && yp <= DM);
        for (int idx = threadIdx.x; idx < PD * 32; idx += 256) {
            int i = idx & 31, xp = idx >> 5;
            float v = 0.0f;
            if (inz && xp >= 1 && xp <= DM)
                v = x[(size_t)(b * CIN + i) * NVOL +
                      (zp - 1) * NPTS + (yp - 1) * DM + (xp - 1)];
            row[idx] = __float2bfloat16(v);
        }
        return;
    }
    // ---- prep role ----
    int idx = (bid - REPACK_BLOCKS) * 256 + threadIdx.x;
    __hip_bfloat16* wfrag = (__hip_bfloat16*)(ws + WS_WFRAG);
    if (idx < NW_ELEMS) {
        int j    = idx & 7;
        int lane = (idx >> 3) & 63;
        int tap  = (idx >> 9) % 27;
        int nt   = (idx / (27 * 512)) & 1;
        int b    = idx / (2 * 27 * 512);
        int o = nt * 16 + (lane & 15);
        int i = (lane >> 4) * 8 + j;
        float e0 = emb[b];
        float w = 0.0f;
        #pragma unroll
        for (int e = 0; e < 3; ++e) {
            float r = 1.0f / (1.0f + expf(-(e0 * rw[e] + rb[e])));
            w += r * ek[((e * COUT + o) * CIN + i) * 27 + tap];
        }
        wfrag[idx] = __float2bfloat16(w);
    } else if (idx < NW_ELEMS + 64) {
        int j2 = idx - NW_ELEMS;
        int b = j2 >> 5, o = j2 & 31;
        float e0 = emb[b];
        float bv = 0.0f;
        #pragma unroll
        for (int e = 0; e < 3; ++e) {
            float r = 1.0f / (1.0f + expf(-(e0 * rw[e] + rb[e])));
            bv += r * ebias[e * COUT + o];
        }
        ws[WS_BCOMB + j2] = bv;
    } else if (idx < PREP_ELEMS) {
        ws[WS_SUM2 + (idx - NW_ELEMS - 64)] = 0.0f;   // zero sums2[64][64]
    }
}

// ---------------------------------------------------------------------------
// Kernel 2: implicit-GEMM conv via MFMA bf16. 64-m blocks: each wave holds
// 2 A-frags (m, m+16) against 1 shared B-frag per tap (load:MFMA = 1.5).
// grid (mc=25, z=40, b=2), block 256 = 4 waves; wave: mt=wv&1, nt=wv>>1
// ---------------------------------------------------------------------------
__global__ __launch_bounds__(256, 4) void conv_mfma_kernel(
        const __hip_bfloat16* __restrict__ xp2,
        const bf16x8* __restrict__ wfrag,
        const float* __restrict__ bcomb,
        __hip_bfloat16* __restrict__ y,
        float* __restrict__ sums2) {
    const int mc = blockIdx.x, z = blockIdx.y, b = blockIdx.z;
    const int tid = threadIdx.x, lane = tid & 63, wv = tid >> 6;
    const int mt = wv & 1, nt = wv >> 1;
    const int quad = lane >> 4, l15 = lane & 15;

    __shared__ float lstat[64];
    if (tid < 64) lstat[tid] = 0.0f;
    __syncthreads();

    // Two A-fragment rows per lane: spatial points pa0, pa0+16
    const int pa0 = mc * 64 + mt * 32 + l15;
    const int pa1 = pa0 + 16;
    const int ya0 = pa0 / DM, xa0 = pa0 % DM;
    const int ya1 = pa1 / DM, xa1 = pa1 % DM;
    const char* abase0 = (const char*)xp2 +
        ((((size_t)b * PD + z) * PD + ya0) * PD + xa0) * 64 + quad * 16;
    const char* abase1 = (const char*)xp2 +
        ((((size_t)b * PD + z) * PD + ya1) * PD + xa1) * 64 + quad * 16;
    // B fragments: pre-shuffled, lane-indexed
    const bf16x8* wbase = wfrag + ((b * 2 + nt) * 27) * 64 + lane;

    floatx4 acc0 = {0.f, 0.f, 0.f, 0.f};
    floatx4 acc1 = {0.f, 0.f, 0.f, 0.f};
    #pragma unroll
    for (int t = 0; t < 27; ++t) {
        const int dz = t / 9, dy = (t / 3) % 3, dx = t % 3;
        const int aoff = ((dz * PD + dy) * PD + dx) * 64;
        bf16x8 av0 = *(const bf16x8*)(abase0 + aoff);
        bf16x8 av1 = *(const bf16x8*)(abase1 + aoff);
        bf16x8 bv  = wbase[t * 64];
        acc0 = __builtin_amdgcn_mfma_f32_16x16x32_bf16(av0, bv, acc0, 0, 0, 0);
        acc1 = __builtin_amdgcn_mfma_f32_16x16x32_bf16(av1, bv, acc1, 0, 0, 0);
    }

    // Epilogue: D[m=quad*4+reg][n=l15]; lane's values share out-channel o
    const int o = nt * 16 + l15;
    const float bias = bcomb[b * COUT + o];
    const int po0 = mc * 64 + mt * 32 + quad * 4;
    const int po1 = po0 + 16;

    float u0 = acc0[0] + bias, u1 = acc0[1] + bias;
    float u2 = acc0[2] + bias, u3 = acc0[3] + bias;
    float w0 = acc1[0] + bias, w1 = acc1[1] + bias;
    float w2 = acc1[2] + bias, w3 = acc1[3] + bias;

    __hip_bfloat16* yrow = y + ((size_t)(b * COUT + o) * DM + z) * NPTS;
    bf16x4 p0 = { f2bf(u0), f2bf(u1), f2bf(u2), f2bf(u3) };
    bf16x4 p1 = { f2bf(w0), f2bf(w1), f2bf(w2), f2bf(w3) };
    *(bf16x4*)(yrow + po0) = p0;
    *(bf16x4*)(yrow + po1) = p1;

    // Wave-level stat reduce: lanes l, l+16, l+32, l+48 share o
    float vs = u0 + u1 + u2 + u3 + w0 + w1 + w2 + w3;
    float vq = u0*u0 + u1*u1 + u2*u2 + u3*u3 + w0*w0 + w1*w1 + w2*w2 + w3*w3;
    vs += __shfl_xor(vs, 16); vq += __shfl_xor(vq, 16);
    vs += __shfl_xor(vs, 32); vq += __shfl_xor(vq, 32);
    if (lane < 16) {
        atomicAdd(&lstat[o],      vs);
        atomicAdd(&lstat[32 + o], vq);
    }
    __syncthreads();
    if (tid < 64) {
        int slot = ((b * DM + z) * 25 + mc) & (NSLOT - 1);
        atomicAdd(&sums2[slot * 64 + tid], lstat[tid]);  // spread: 4096 addrs
    }
}

// ---------------------------------------------------------------------------
// Kernel 3: reduce stat slots -> BN params; BN apply + LeakyReLU + upsample x2
// 4 source voxels per thread; 8x nontemporal floatx4 stores. grid 4000 x 256.
// ---------------------------------------------------------------------------
__global__ void upsample_kernel(const __hip_bfloat16* __restrict__ yin,
                                const float* __restrict__ sums2,
                                const float* __restrict__ gamma,
                                const float* __restrict__ beta,
                                float* __restrict__ out) {
    __shared__ float partl[4][64];
    __shared__ float ssc[32], ssh[32];
    const int tid = threadIdx.x;
    {   // 256 threads: group sg reduces 16 slots for stat st
        int sg = tid >> 6, st = tid & 63;
        float p = 0.0f;
        #pragma unroll
        for (int s = 0; s < 16; ++s) p += sums2[(sg * 16 + s) * 64 + st];
        partl[sg][st] = p;
    }
    __syncthreads();
    if (tid < 64) {
        partl[0][tid] += partl[1][tid] + partl[2][tid] + partl[3][tid];
    }
    __syncthreads();
    if (tid < 32) {
        const float invN = 1.0f / (float)(BB * NVOL);
        float mean  = partl[0][tid] * invN;
        float var   = partl[0][32 + tid] * invN - mean * mean;
        float scale = gamma[tid] * rsqrtf(var + EPSBN);
        ssc[tid] = scale;
        ssh[tid] = beta[tid] - mean * scale;
    }
    __syncthreads();

    int idx = blockIdx.x * 256 + tid;        // 0 .. 1,024,000
    int cc = idx / (NVOL / 4);               // b*COUT + c
    int p  = idx % (NVOL / 4);
    int z  = p / (NPTS / 4);
    int yy = (p / (DM / 4)) % DM;
    int x4 = p % (DM / 4);                   // quad index: src x = 4*x4 .. +3
    int c  = cc & 31;

    bf16x4 rv = *(const bf16x4*)(yin + (size_t)idx * 4);
    float sc = ssc[c], sh = ssh[c];
    float v0 = bf2f(rv[0]) * sc + sh; v0 = (v0 >= 0.0f) ? v0 : 0.1f * v0;
    float v1 = bf2f(rv[1]) * sc + sh; v1 = (v1 >= 0.0f) ? v1 : 0.1f * v1;
    float v2 = bf2f(rv[2]) * sc + sh; v2 = (v2 >= 0.0f) ? v2 : 0.1f * v2;
    float v3 = bf2f(rv[3]) * sc + sh; v3 = (v3 >= 0.0f) ? v3 : 0.1f * v3;

    floatx4 q01 = {v0, v0, v1, v1};
    floatx4 q23 = {v2, v2, v3, v3};
    size_t obase = ((size_t)cc * 80 + (size_t)(2 * z)) * 6400
                 + (size_t)(2 * yy) * 80 + (size_t)(8 * x4);
    __builtin_nontemporal_store(q01, (floatx4*)(out + obase));
    __builtin_nontemporal_store(q23, (floatx4*)(out + obase + 4));
    __builtin_nontemporal_store(q01, (floatx4*)(out + obase + 80));
    __builtin_nontemporal_store(q23, (floatx4*)(out + obase + 84));
    __builtin_nontemporal_store(q01, (floatx4*)(out + obase + 6400));
    __builtin_nontemporal_store(q23, (floatx4*)(out + obase + 6404));
    __builtin_nontemporal_store(q01, (floatx4*)(out + obase + 6480));
    __builtin_nontemporal_store(q23, (floatx4*)(out + obase + 6484));
}

// ---------------------------------------------------------------------------
extern "C" void kernel_launch(void* const* d_in, const int* in_sizes, int n_in,
                              void* d_out, int out_size, void* d_ws, size_t ws_size,
                              hipStream_t stream) {
    const float* x     = (const float*)d_in[0];
    const float* emb   = (const float*)d_in[1];
    const float* rw    = (const float*)d_in[2];
    const float* rb    = (const float*)d_in[3];
    const float* ek    = (const float*)d_in[4];
    const float* ebias = (const float*)d_in[5];
    const float* gamma = (const float*)d_in[6];
    const float* beta  = (const float*)d_in[7];
    float* ws  = (float*)d_ws;
    float* out = (float*)d_out;

    // 1: prep + repack (+ zero stat slots)
    prep_repack_kernel<<<REPACK_BLOCKS + PREP_BLOCKS, 256, 0, stream>>>(
        x, emb, rw, rb, ek, ebias, ws);

    // 2: MFMA conv (bf16 y) + slot-spread stats
    conv_mfma_kernel<<<dim3(25, DM, BB), 256, 0, stream>>>(
        (const __hip_bfloat16*)(ws + WS_XPAD2), (const bf16x8*)(ws + WS_WFRAG),
        ws + WS_BCOMB, (__hip_bfloat16*)(ws + WS_Y), ws + WS_SUM2);

    // 3: reduce slots + BN params + apply + LeakyReLU + upsample (nt stores)
    upsample_kernel<<<(BB * COUT * NVOL / 4) / 256, 256, 0, stream>>>(
        (const __hip_bfloat16*)(ws + WS_Y), ws + WS_SUM2, gamma, beta, out);
}

// Round 7
// 203.243 us; speedup vs baseline: 1.1558x; 1.1558x over previous
//
#include <hip/hip_runtime.h>
#include <hip/hip_bf16.h>
#include <math.h>

// Problem constants
#define BB   2
#define CIN  32
#define COUT 32
#define DM   40
#define PD   42                 // padded spatial dim
#define NPTS (DM*DM)            // 1600
#define NVOL (DM*DM*DM)         // 64000
#define EPSBN 1e-5f
#define NSLOT 64                // stat-accumulator slots (spread atomics)

typedef short  bf16x8  __attribute__((ext_vector_type(8)));
typedef short  bf16x4  __attribute__((ext_vector_type(4)));
typedef float  floatx4 __attribute__((ext_vector_type(4)));

// Workspace layout (float offsets), all 16B-aligned
#define WS_WFRAG 0              // bf16[55296] = 27648 floats
#define WS_BCOMB 27648          // 64 floats
#define WS_SUM2  27712          // 64 slots * 64 stats = 4096 floats
#define WS_XPAD2 31808          // bf16[2*42^3*32] = 2370816 floats
#define WS_Y     2402624        // bf16[2*32*64000] = 2048000 floats

#define REPACK_BLOCKS (PD*PD*BB)                  // 3528
#define NW_ELEMS  (2*2*27*64*8)                   // 55296
#define PREP_ELEMS (NW_ELEMS + 64 + NSLOT*64)     // wfrag + bias + zero sums2
#define PREP_BLOCKS ((PREP_ELEMS + 255) / 256)    // 233

static __device__ __forceinline__ short f2bf(float f) {
    __hip_bfloat16 h = __float2bfloat16(f);
    return *reinterpret_cast<short*>(&h);
}
static __device__ __forceinline__ float bf2f(short s) {
    union { unsigned u; float f; } cv;
    cv.u = ((unsigned)(unsigned short)s) << 16;
    return cv.f;
}

// ---------------------------------------------------------------------------
// Kernel 1: fused prep (routing + B-fragment weights + bias + zero stat slots)
//           and channels-last zero-padded bf16 repack of x.
// wfrag[b][ntile][tap][lane][j] = W_b[i=(lane>>4)*8+j][o=ntile*16+(lane&15)][tap]
// ---------------------------------------------------------------------------
__global__ void prep_repack_kernel(const float* __restrict__ x,
                                   const float* __restrict__ emb,
                                   const float* __restrict__ rw,
                                   const float* __restrict__ rb,
                                   const float* __restrict__ ek,
                                   const float* __restrict__ ebias,
                                   float* __restrict__ ws) {
    const int bid = blockIdx.x;
    if (bid < REPACK_BLOCKS) {
        // ---- repack role ----
        int b  = bid / (PD * PD);
        int r  = bid % (PD * PD);
        int zp = r / PD, yp = r % PD;
        __hip_bfloat16* row = (__hip_bfloat16*)(ws + WS_XPAD2) +
                              ((((size_t)b * PD + zp) * PD + yp) * PD) * 32;
        bool inz = (zp >= 1 && zp <= DM && yp >= 1 && yp <= DM);
        for (int idx = threadIdx.x; idx < PD * 32; idx += 256) {
            int i = idx & 31, xp = idx >> 5;
            float v = 0.0f;
            if (inz && xp >= 1 && xp <= DM)
                v = x[(size_t)(b * CIN + i) * NVOL +
                      (zp - 1) * NPTS + (yp - 1) * DM + (xp - 1)];
            row[idx] = __float2bfloat16(v);
        }
        return;
    }
    // ---- prep role ----
    int idx = (bid - REPACK_BLOCKS) * 256 + threadIdx.x;
    __hip_bfloat16* wfrag = (__hip_bfloat16*)(ws + WS_WFRAG);
    if (idx < NW_ELEMS) {
        int j    = idx & 7;
        int lane = (idx >> 3) & 63;
        int tap  = (idx >> 9) % 27;
        int nt   = (idx / (27 * 512)) & 1;
        int b    = idx / (2 * 27 * 512);
        int o = nt * 16 + (lane & 15);
        int i = (lane >> 4) * 8 + j;
        float e0 = emb[b];
        float w = 0.0f;
        #pragma unroll
        for (int e = 0; e < 3; ++e) {
            float r = 1.0f / (1.0f + expf(-(e0 * rw[e] + rb[e])));
            w += r * ek[((e * COUT + o) * CIN + i) * 27 + tap];
        }
        wfrag[idx] = __float2bfloat16(w);
    } else if (idx < NW_ELEMS + 64) {
        int j2 = idx - NW_ELEMS;
        int b = j2 >> 5, o = j2 & 31;
        float e0 = emb[b];
        float bv = 0.0f;
        #pragma unroll
        for (int e = 0; e < 3; ++e) {
            float r = 1.0f / (1.0f + expf(-(e0 * rw[e] + rb[e])));
            bv += r * ebias[e * COUT + o];
        }
        ws[WS_BCOMB + j2] = bv;
    } else if (idx < PREP_ELEMS) {
        ws[WS_SUM2 + (idx - NW_ELEMS - 64)] = 0.0f;   // zero sums2[64][64]
    }
}

// ---------------------------------------------------------------------------
// Kernel 2: implicit-GEMM conv via MFMA bf16. 64-m blocks: each wave holds
// 2 A-frags (m, m+16) against 1 shared B-frag per tap (load:MFMA = 1.5).
// grid (mc=25, z=40, b=2), block 256 = 4 waves; wave: mt=wv&1, nt=wv>>1
// ---------------------------------------------------------------------------
__global__ __launch_bounds__(256, 4) void conv_mfma_kernel(
        const __hip_bfloat16* __restrict__ xp2,
        const bf16x8* __restrict__ wfrag,
        const float* __restrict__ bcomb,
        __hip_bfloat16* __restrict__ y,
        float* __restrict__ sums2) {
    const int mc = blockIdx.x, z = blockIdx.y, b = blockIdx.z;
    const int tid = threadIdx.x, lane = tid & 63, wv = tid >> 6;
    const int mt = wv & 1, nt = wv >> 1;
    const int quad = lane >> 4, l15 = lane & 15;

    __shared__ float lstat[64];
    if (tid < 64) lstat[tid] = 0.0f;
    __syncthreads();

    // Two A-fragment rows per lane: spatial points pa0, pa0+16
    const int pa0 = mc * 64 + mt * 32 + l15;
    const int pa1 = pa0 + 16;
    const int ya0 = pa0 / DM, xa0 = pa0 % DM;
    const int ya1 = pa1 / DM, xa1 = pa1 % DM;
    const char* abase0 = (const char*)xp2 +
        ((((size_t)b * PD + z) * PD + ya0) * PD + xa0) * 64 + quad * 16;
    const char* abase1 = (const char*)xp2 +
        ((((size_t)b * PD + z) * PD + ya1) * PD + xa1) * 64 + quad * 16;
    // B fragments: pre-shuffled, lane-indexed
    const bf16x8* wbase = wfrag + ((b * 2 + nt) * 27) * 64 + lane;

    floatx4 acc0 = {0.f, 0.f, 0.f, 0.f};
    floatx4 acc1 = {0.f, 0.f, 0.f, 0.f};
    #pragma unroll
    for (int t = 0; t < 27; ++t) {
        const int dz = t / 9, dy = (t / 3) % 3, dx = t % 3;
        const int aoff = ((dz * PD + dy) * PD + dx) * 64;
        bf16x8 av0 = *(const bf16x8*)(abase0 + aoff);
        bf16x8 av1 = *(const bf16x8*)(abase1 + aoff);
        bf16x8 bv  = wbase[t * 64];
        acc0 = __builtin_amdgcn_mfma_f32_16x16x32_bf16(av0, bv, acc0, 0, 0, 0);
        acc1 = __builtin_amdgcn_mfma_f32_16x16x32_bf16(av1, bv, acc1, 0, 0, 0);
    }

    // Epilogue: D[m=quad*4+reg][n=l15]; lane's values share out-channel o
    const int o = nt * 16 + l15;
    const float bias = bcomb[b * COUT + o];
    const int po0 = mc * 64 + mt * 32 + quad * 4;
    const int po1 = po0 + 16;

    float u0 = acc0[0] + bias, u1 = acc0[1] + bias;
    float u2 = acc0[2] + bias, u3 = acc0[3] + bias;
    float w0 = acc1[0] + bias, w1 = acc1[1] + bias;
    float w2 = acc1[2] + bias, w3 = acc1[3] + bias;

    __hip_bfloat16* yrow = y + ((size_t)(b * COUT + o) * DM + z) * NPTS;
    bf16x4 p0 = { f2bf(u0), f2bf(u1), f2bf(u2), f2bf(u3) };
    bf16x4 p1 = { f2bf(w0), f2bf(w1), f2bf(w2), f2bf(w3) };
    *(bf16x4*)(yrow + po0) = p0;
    *(bf16x4*)(yrow + po1) = p1;

    // Wave-level stat reduce: lanes l, l+16, l+32, l+48 share o
    float vs = u0 + u1 + u2 + u3 + w0 + w1 + w2 + w3;
    float vq = u0*u0 + u1*u1 + u2*u2 + u3*u3 + w0*w0 + w1*w1 + w2*w2 + w3*w3;
    vs += __shfl_xor(vs, 16); vq += __shfl_xor(vq, 16);
    vs += __shfl_xor(vs, 32); vq += __shfl_xor(vq, 32);
    if (lane < 16) {
        atomicAdd(&lstat[o],      vs);
        atomicAdd(&lstat[32 + o], vq);
    }
    __syncthreads();
    if (tid < 64) {
        int slot = ((b * DM + z) * 25 + mc) & (NSLOT - 1);
        atomicAdd(&sums2[slot * 64 + tid], lstat[tid]);  // spread: 4096 addrs
    }
}

// ---------------------------------------------------------------------------
// Kernel 3: reduce stat slots -> BN params; BN apply + LeakyReLU + upsample x2
// 4 source voxels per thread; 8x cached floatx4 stores (L3 absorbs the
// write stream and defers HBM writeback — NT stores regressed 20 µs).
// grid 4000 x 256.
// ---------------------------------------------------------------------------
__global__ void upsample_kernel(const __hip_bfloat16* __restrict__ yin,
                                const float* __restrict__ sums2,
                                const float* __restrict__ gamma,
                                const float* __restrict__ beta,
                                float* __restrict__ out) {
    __shared__ float partl[4][64];
    __shared__ float ssc[32], ssh[32];
    const int tid = threadIdx.x;
    {   // 256 threads: group sg reduces 16 slots for stat st
        int sg = tid >> 6, st = tid & 63;
        float p = 0.0f;
        #pragma unroll
        for (int s = 0; s < 16; ++s) p += sums2[(sg * 16 + s) * 64 + st];
        partl[sg][st] = p;
    }
    __syncthreads();
    if (tid < 64) {
        partl[0][tid] += partl[1][tid] + partl[2][tid] + partl[3][tid];
    }
    __syncthreads();
    if (tid < 32) {
        const float invN = 1.0f / (float)(BB * NVOL);
        float mean  = partl[0][tid] * invN;
        float var   = partl[0][32 + tid] * invN - mean * mean;
        float scale = gamma[tid] * rsqrtf(var + EPSBN);
        ssc[tid] = scale;
        ssh[tid] = beta[tid] - mean * scale;
    }
    __syncthreads();

    int idx = blockIdx.x * 256 + tid;        // 0 .. 1,024,000
    int cc = idx / (NVOL / 4);               // b*COUT + c
    int p  = idx % (NVOL / 4);
    int z  = p / (NPTS / 4);
    int yy = (p / (DM / 4)) % DM;
    int x4 = p % (DM / 4);                   // quad index: src x = 4*x4 .. +3
    int c  = cc & 31;

    bf16x4 rv = *(const bf16x4*)(yin + (size_t)idx * 4);
    float sc = ssc[c], sh = ssh[c];
    float v0 = bf2f(rv[0]) * sc + sh; v0 = (v0 >= 0.0f) ? v0 : 0.1f * v0;
    float v1 = bf2f(rv[1]) * sc + sh; v1 = (v1 >= 0.0f) ? v1 : 0.1f * v1;
    float v2 = bf2f(rv[2]) * sc + sh; v2 = (v2 >= 0.0f) ? v2 : 0.1f * v2;
    float v3 = bf2f(rv[3]) * sc + sh; v3 = (v3 >= 0.0f) ? v3 : 0.1f * v3;

    floatx4 q01 = {v0, v0, v1, v1};
    floatx4 q23 = {v2, v2, v3, v3};
    size_t obase = ((size_t)cc * 80 + (size_t)(2 * z)) * 6400
                 + (size_t)(2 * yy) * 80 + (size_t)(8 * x4);
    *(floatx4*)(out + obase)        = q01;
    *(floatx4*)(out + obase + 4)    = q23;
    *(floatx4*)(out + obase + 80)   = q01;
    *(floatx4*)(out + obase + 84)   = q23;
    *(floatx4*)(out + obase + 6400) = q01;
    *(floatx4*)(out + obase + 6404) = q23;
    *(floatx4*)(out + obase + 6480) = q01;
    *(floatx4*)(out + obase + 6484) = q23;
}

// ---------------------------------------------------------------------------
extern "C" void kernel_launch(void* const* d_in, const int* in_sizes, int n_in,
                              void* d_out, int out_size, void* d_ws, size_t ws_size,
                              hipStream_t stream) {
    const float* x     = (const float*)d_in[0];
    const float* emb   = (const float*)d_in[1];
    const float* rw    = (const float*)d_in[2];
    const float* rb    = (const float*)d_in[3];
    const float* ek    = (const float*)d_in[4];
    const float* ebias = (const float*)d_in[5];
    const float* gamma = (const float*)d_in[6];
    const float* beta  = (const float*)d_in[7];
    float* ws  = (float*)d_ws;
    float* out = (float*)d_out;

    // 1: prep + repack (+ zero stat slots)
    prep_repack_kernel<<<REPACK_BLOCKS + PREP_BLOCKS, 256, 0, stream>>>(
        x, emb, rw, rb, ek, ebias, ws);

    // 2: MFMA conv (bf16 y) + slot-spread stats
    conv_mfma_kernel<<<dim3(25, DM, BB), 256, 0, stream>>>(
        (const __hip_bfloat16*)(ws + WS_XPAD2), (const bf16x8*)(ws + WS_WFRAG),
        ws + WS_BCOMB, (__hip_bfloat16*)(ws + WS_Y), ws + WS_SUM2);

    // 3: reduce slots + BN params + apply + LeakyReLU + upsample (cached stores)
    upsample_kernel<<<(BB * COUT * NVOL / 4) / 256, 256, 0, stream>>>(
        (const __hip_bfloat16*)(ws + WS_Y), ws + WS_SUM2, gamma, beta, out);
}